// Round 4
// baseline (104.328 us; speedup 1.0000x reference)
//
#include <hip/hip_runtime.h>
#include <math.h>

#define N_B 2
#define HH 48
#define WW 48
#define DM 256
#define NH 4
#define EH 64
#define KS 7
#define NPIX (N_B*HH*WW)    // 4608

typedef _Float16 half8 __attribute__((ext_vector_type(8)));
typedef _Float16 half4v __attribute__((ext_vector_type(4)));
typedef float float4v __attribute__((ext_vector_type(4)));

// ---------------- prep: scale = cond @ w_norm.T + 1, and fp32->fp16 weights ----------------
__global__ __launch_bounds__(256) void prep_kernel(const float* __restrict__ cond,
                                                   const float* __restrict__ w_norm,
                                                   const float* __restrict__ w_qkv,
                                                   const float* __restrict__ w_out,
                                                   float* __restrict__ scale,
                                                   _Float16* __restrict__ wqkv_h,
                                                   _Float16* __restrict__ wout_h) {
    int bid = blockIdx.x, t = threadIdx.x;
    if (bid < 16) {
        int wave = t >> 6, lane = t & 63;
        int b = bid >> 3;
        int d = (bid & 7)*32 + wave*8 + (lane >> 3);
        int l8 = lane & 7;
        const float4* wr4 = (const float4*)(w_norm + (size_t)d*DM) + l8*8;
        const float4* c4  = (const float4*)(cond + (size_t)b*DM) + l8*8;
        float acc = 0.f;
        #pragma unroll
        for (int j = 0; j < 8; ++j) {
            float4 w = wr4[j], c = c4[j];
            acc += w.x*c.x + w.y*c.y + w.z*c.z + w.w*c.w;
        }
        acc += __shfl_xor(acc, 1, 64);
        acc += __shfl_xor(acc, 2, 64);
        acc += __shfl_xor(acc, 4, 64);
        if (l8 == 0) scale[b*DM + d] = acc + 1.0f;
    } else if (bid < 40) {
        int job = bid - 16;
        const float* src = w_qkv + (size_t)job*8192;
        _Float16* dst = wqkv_h + (size_t)job*8192;
        #pragma unroll
        for (int j = 0; j < 8; ++j) {
            int idx = (j*256 + t)*4;
            float4 v = *(const float4*)(src + idx);
            half4v h;
            h[0] = (_Float16)v.x; h[1] = (_Float16)v.y;
            h[2] = (_Float16)v.z; h[3] = (_Float16)v.w;
            *(half4v*)(dst + idx) = h;
        }
    } else {
        int job = bid - 40;
        const float* src = w_out + (size_t)job*8192;
        _Float16* dst = wout_h + (size_t)job*8192;
        #pragma unroll
        for (int j = 0; j < 8; ++j) {
            int idx = (j*256 + t)*4;
            float4 v = *(const float4*)(src + idx);
            half4v h;
            h[0] = (_Float16)v.x; h[1] = (_Float16)v.y;
            h[2] = (_Float16)v.z; h[3] = (_Float16)v.w;
            *(half4v*)(dst + idx) = h;
        }
    }
}

// ---------------- fused RMSNorm + QKV GEMM + RoPE (fp16 B, vectorized store) ----------------
__global__ __launch_bounds__(256) void gemm_qkv_fused(const float* __restrict__ x,
                                                      const float* __restrict__ scale,
                                                      const _Float16* __restrict__ B,
                                                      const float* __restrict__ pos,
                                                      _Float16* __restrict__ qh,
                                                      _Float16* __restrict__ kh,
                                                      _Float16* __restrict__ vh) {
    const int LDA = 264, LDB = 40, LDO = 136;
    __shared__ _Float16 As[64*LDA];
    __shared__ _Float16 Bs[2][128*LDB];
    int t = threadIdx.x;
    int wave = t >> 6, lane = t & 63;
    int m0 = blockIdx.x*64;
    int n0 = blockIdx.y*128;            // by in 0..5
    int b  = m0 / (HH*WW);

    // ---- load x rows, RMS-normalize, write fp16 As (full K) ----
    {
        int tr = t >> 2, c4i = t & 3;   // 4 threads per row
        const float4* xr = (const float4*)(x + (size_t)(m0 + tr)*DM);
        float4 xv[16];
        float ss = 0.f;
        #pragma unroll
        for (int j = 0; j < 16; ++j) {
            xv[j] = xr[c4i + j*4];
            ss += xv[j].x*xv[j].x + xv[j].y*xv[j].y + xv[j].z*xv[j].z + xv[j].w*xv[j].w;
        }
        ss += __shfl_xor(ss, 1, 64);
        ss += __shfl_xor(ss, 2, 64);
        float r = rsqrtf(ss*(1.0f/DM) + 1e-6f);
        const float* sc = scale + b*DM;
        #pragma unroll
        for (int j = 0; j < 16; ++j) {
            int c = (c4i + j*4)*4;
            float4 s4 = *(const float4*)(sc + c);
            half4v h;
            h[0] = (_Float16)(xv[j].x * s4.x * r);
            h[1] = (_Float16)(xv[j].y * s4.y * r);
            h[2] = (_Float16)(xv[j].z * s4.z * r);
            h[3] = (_Float16)(xv[j].w * s4.w * r);
            *(half4v*)&As[tr*LDA + c] = h;
        }
    }
    // ---- stage Bs[0]: 128 rows x 32 k (half8 copies) ----
    int br = t >> 1, kk = (t & 1)*16;
    {
        const _Float16* bp = B + (size_t)(n0 + br)*DM + kk;
        *(half8*)&Bs[0][br*LDB + kk]     = *(const half8*)bp;
        *(half8*)&Bs[0][br*LDB + kk + 8] = *(const half8*)(bp + 8);
    }
    __syncthreads();

    float4v acc[2][4];
    #pragma unroll
    for (int mi = 0; mi < 2; ++mi)
        #pragma unroll
        for (int ni = 0; ni < 4; ++ni) acc[mi][ni] = (float4v){0.f,0.f,0.f,0.f};

    int frow = lane & 15, kq = (lane >> 4)*8;
    int wm = wave >> 1, wn = wave & 1;

    for (int it = 0; it < 8; ++it) {
        int cur = it & 1;
        half8 nb0, nb1;
        if (it < 7) {
            const _Float16* bp = B + (size_t)(n0 + br)*DM + (it + 1)*32 + kk;
            nb0 = *(const half8*)bp;
            nb1 = *(const half8*)(bp + 8);
        }
        int ka = it*32 + kq;
        half8 af0 = *(const half8*)&As[(wm*32 +  0 + frow)*LDA + ka];
        half8 af1 = *(const half8*)&As[(wm*32 + 16 + frow)*LDA + ka];
        #pragma unroll
        for (int ni = 0; ni < 4; ++ni) {
            half8 bf = *(const half8*)&Bs[cur][(wn*64 + ni*16 + frow)*LDB + kq];
            acc[0][ni] = __builtin_amdgcn_mfma_f32_16x16x32_f16(af0, bf, acc[0][ni], 0, 0, 0);
            acc[1][ni] = __builtin_amdgcn_mfma_f32_16x16x32_f16(af1, bf, acc[1][ni], 0, 0, 0);
        }
        if (it < 7) {
            *(half8*)&Bs[cur^1][br*LDB + kk]     = nb0;
            *(half8*)&Bs[cur^1][br*LDB + kk + 8] = nb1;
            __syncthreads();
        }
    }

    // Epilogue: RoPE in registers, stage to LDS, store vectorized.
    // tile-col = wn*64 + ni*16 + col; head = (by&1)*2 + (tilecol>>6); e = tilecol&63.
    int sel  = blockIdx.y >> 1;
    _Float16* outp = (sel == 0) ? qh : (sel == 1) ? kh : vh;
    int col = lane & 15, rbase = (lane >> 4)*4;
    float freq = __expf(1.14472988585f + (float)(col & 7) * 0.287823136624f); // pi * 10^(mf/8)

    __syncthreads();                    // all As/Bs reads done; reuse As as OS
    _Float16* OS = As;                  // [64][LDO=136]
    #pragma unroll
    for (int mi = 0; mi < 2; ++mi) {
        #pragma unroll
        for (int r = 0; r < 4; ++r) {
            int pr  = wm*32 + mi*16 + rbase + r;
            int pix = m0 + pr;
            float v0 = acc[mi][0][r], v1 = acc[mi][1][r], v2 = acc[mi][2][r], v3 = acc[mi][3][r];
            if (sel < 2) {
                int hw = pix % (HH*WW);
                float p = (col < 8) ? pos[hw*2] : pos[hw*2+1];
                float sn, cs;
                __sincosf(p*freq, &sn, &cs);
                float o0 = v0*cs - v1*sn;
                float o1 = v1*cs + v0*sn;
                v0 = o0; v1 = o1;
                if (sel == 0) { v0*=0.125f; v1*=0.125f; v2*=0.125f; v3*=0.125f; }
            }
            int cb = wn*64 + col;
            OS[pr*LDO + cb +  0] = (_Float16)v0;
            OS[pr*LDO + cb + 16] = (_Float16)v1;
            OS[pr*LDO + cb + 32] = (_Float16)v2;
            OS[pr*LDO + cb + 48] = (_Float16)v3;
        }
    }
    __syncthreads();
    {
        int pr = t >> 2, c0 = (t & 3)*32;          // 32 cols = 64 B per thread
        int pix  = m0 + pr;
        int head = (blockIdx.y & 1)*2 + (c0 >> 6);
        int e    = c0 & 63;
        _Float16* gp = outp + (size_t)pix*DM + head*EH + e;
        const _Float16* lp = &OS[pr*LDO + c0];
        *(half8*)(gp +  0) = *(const half8*)(lp +  0);
        *(half8*)(gp +  8) = *(const half8*)(lp +  8);
        *(half8*)(gp + 16) = *(const half8*)(lp + 16);
        *(half8*)(gp + 24) = *(const half8*)(lp + 24);
    }
}

// ---------------- MFMA neighborhood attention (deferred 1/sum) ----------------
__global__ __launch_bounds__(256) void attn_mfma(const _Float16* __restrict__ qg,
                                                 const _Float16* __restrict__ kg,
                                                 const _Float16* __restrict__ vg,
                                                 _Float16* __restrict__ obuf) {
    __shared__ _Float16 VT[64*232];   // [d][nb]
    __shared__ _Float16 SP[64*232];   // [q][nb]
    int t = threadIdx.x;
    int wave = t >> 6, lane = t & 63;
    int col = lane & 15, quad = lane >> 4;
    int ty = blockIdx.x / 6, tx = blockIdx.x % 6;
    int b = blockIdx.y >> 2, head = blockIdx.y & 3;
    int qh0 = ty*8, qw0 = tx*8;
    int rh0 = min(max(qh0-3, 0), HH-14);
    int rw0 = min(max(qw0-3, 0), WW-14);

    {
        int nbl = t & 31;
        int e0  = (t >> 5) * 8;
        #pragma unroll
        for (int pass = 0; pass < 7; ++pass) {
            int nb = pass*32 + nbl;
            int nr = nb >> 4, nc = nb & 15;
            int pix = (b*HH + rh0+nr)*WW + rw0 + nc;
            half8 vv = *(const half8*)(vg + (size_t)pix*DM + head*EH + e0);
            #pragma unroll
            for (int i = 0; i < 8; ++i)
                VT[(e0+i)*232 + nb] = vv[i];
        }
    }

    int qidx_a = wave*16 + col;
    int pixq = (b*HH + qh0 + (qidx_a>>3))*WW + qw0 + (qidx_a & 7);
    const _Float16* qp = qg + (size_t)pixq*DM + head*EH;
    half8 qf0 = *(const half8*)(qp + quad*8);
    half8 qf1 = *(const half8*)(qp + 32 + quad*8);

    float4v s[14];
    #pragma unroll
    for (int nr = 0; nr < 14; ++nr) {
        int pixk = (b*HH + rh0+nr)*WW + rw0 + col;
        const _Float16* kp = kg + (size_t)pixk*DM + head*EH;
        half8 kf0 = *(const half8*)(kp + quad*8);
        half8 kf1 = *(const half8*)(kp + 32 + quad*8);
        float4v a = (float4v){0.f,0.f,0.f,0.f};
        a = __builtin_amdgcn_mfma_f32_16x16x32_f16(qf0, kf0, a, 0, 0, 0);
        a = __builtin_amdgcn_mfma_f32_16x16x32_f16(qf1, kf1, a, 0, 0, 0);
        s[nr] = a;
    }

    int sh_[4], uw_[4];
    #pragma unroll
    for (int r = 0; r < 4; ++r) {
        int qidx = wave*16 + quad*4 + r;
        int qhh = qh0 + (qidx>>3), qww = qw0 + (qidx & 7);
        sh_[r] = min(max(qhh-3, 0), HH-KS);
        int sw_ = min(max(qww-3, 0), WW-KS);
        uw_[r] = rw0 + col - sw_;
    }
    #pragma unroll
    for (int nr = 0; nr < 14; ++nr)
        #pragma unroll
        for (int r = 0; r < 4; ++r) {
            int uh = rh0 + nr - sh_[r];
            bool ok = ((unsigned)uh < 7u) && ((unsigned)uw_[r] < 7u);
            s[nr][r] = ok ? s[nr][r] : -1e30f;
        }
    float rs4[4];
    #pragma unroll
    for (int r = 0; r < 4; ++r) {
        float m = s[0][r];
        #pragma unroll
        for (int nr = 1; nr < 14; ++nr) m = fmaxf(m, s[nr][r]);
        m = fmaxf(m, __shfl_xor(m, 1, 64));
        m = fmaxf(m, __shfl_xor(m, 2, 64));
        m = fmaxf(m, __shfl_xor(m, 4, 64));
        m = fmaxf(m, __shfl_xor(m, 8, 64));
        float sum = 0.f;
        #pragma unroll
        for (int nr = 0; nr < 14; ++nr) { float p = __expf(s[nr][r] - m); s[nr][r] = p; sum += p; }
        sum += __shfl_xor(sum, 1, 64);
        sum += __shfl_xor(sum, 2, 64);
        sum += __shfl_xor(sum, 4, 64);
        sum += __shfl_xor(sum, 8, 64);
        rs4[r] = 1.f / sum;
        #pragma unroll
        for (int nr = 0; nr < 14; ++nr)
            SP[(wave*16 + quad*4 + r)*232 + nr*16 + col] = (_Float16)s[nr][r];
    }
    __syncthreads();

    float4v o[4];
    #pragma unroll
    for (int dt = 0; dt < 4; ++dt) o[dt] = (float4v){0.f,0.f,0.f,0.f};
    #pragma unroll
    for (int ks = 0; ks < 7; ++ks) {
        half8 pa = *(const half8*)&SP[(wave*16 + col)*232 + ks*32 + quad*8];
        #pragma unroll
        for (int dt = 0; dt < 4; ++dt) {
            half8 vf = *(const half8*)&VT[(dt*16 + col)*232 + ks*32 + quad*8];
            o[dt] = __builtin_amdgcn_mfma_f32_16x16x32_f16(pa, vf, o[dt], 0, 0, 0);
        }
    }
    #pragma unroll
    for (int r = 0; r < 4; ++r) {
        int qidx = wave*16 + quad*4 + r;
        int pix = (b*HH + qh0 + (qidx>>3))*WW + qw0 + (qidx & 7);
        #pragma unroll
        for (int dt = 0; dt < 4; ++dt)
            obuf[(size_t)pix*DM + head*EH + dt*16 + col] = (_Float16)(o[dt][r] * rs4[r]);
    }
}

// ---------------- out GEMM: C = obuf @ w_out^T + skip (fp16 B, vectorized epilogue) ----------------
__global__ __launch_bounds__(256) void gemm_out_f16(const _Float16* __restrict__ A,
                                                    const _Float16* __restrict__ B,
                                                    float* __restrict__ C,
                                                    const float* __restrict__ skip) {
    const int LDA = 264, LDB = 40, LDO = 68;
    __shared__ _Float16 As[64*LDA];
    __shared__ _Float16 Bs[2][64*LDB];
    int t = threadIdx.x;
    int wave = t >> 6, lane = t & 63;
    int m0 = blockIdx.x*64, n0 = blockIdx.y*64;

    // stage full A tile (fp16 copy)
    {
        int tr = t >> 2, c8 = (t & 3)*8;
        const _Float16* ap = A + (size_t)(m0 + tr)*DM;
        #pragma unroll
        for (int j = 0; j < 8; ++j)
            *(half8*)&As[tr*LDA + c8 + j*32] = *(const half8*)(ap + c8 + j*32);
    }
    // stage Bs[0]: 64 rows x 32 k (half8 copy)
    int br = t >> 2, kk = (t & 3)*8;
    *(half8*)&Bs[0][br*LDB + kk] = *(const half8*)(B + (size_t)(n0 + br)*DM + kk);
    __syncthreads();

    float4v acc[2][2];
    #pragma unroll
    for (int mi = 0; mi < 2; ++mi)
        #pragma unroll
        for (int ni = 0; ni < 2; ++ni) acc[mi][ni] = (float4v){0.f,0.f,0.f,0.f};

    int frow = lane & 15, kq = (lane >> 4)*8;
    int wm = wave >> 1, wn = wave & 1;

    for (int it = 0; it < 8; ++it) {
        int cur = it & 1;
        half8 nb;
        if (it < 7)
            nb = *(const half8*)(B + (size_t)(n0 + br)*DM + (it + 1)*32 + kk);
        int ka = it*32 + kq;
        half8 af0 = *(const half8*)&As[(wm*32 +  0 + frow)*LDA + ka];
        half8 af1 = *(const half8*)&As[(wm*32 + 16 + frow)*LDA + ka];
        #pragma unroll
        for (int ni = 0; ni < 2; ++ni) {
            half8 bf = *(const half8*)&Bs[cur][(wn*32 + ni*16 + frow)*LDB + kq];
            acc[0][ni] = __builtin_amdgcn_mfma_f32_16x16x32_f16(af0, bf, acc[0][ni], 0, 0, 0);
            acc[1][ni] = __builtin_amdgcn_mfma_f32_16x16x32_f16(af1, bf, acc[1][ni], 0, 0, 0);
        }
        if (it < 7) {
            *(half8*)&Bs[cur^1][br*LDB + kk] = nb;
            __syncthreads();
        }
    }

    // Epilogue: stage fp32 tile to LDS, add skip + store vectorized.
    int col = lane & 15, rbase = (lane >> 4)*4;
    __syncthreads();                    // As/Bs reads done; reuse As as fp32 OS
    float* OS = (float*)As;             // [64][LDO=68]
    #pragma unroll
    for (int mi = 0; mi < 2; ++mi) {
        #pragma unroll
        for (int ni = 0; ni < 2; ++ni) {
            #pragma unroll
            for (int r = 0; r < 4; ++r) {
                int rt = wm*32 + mi*16 + rbase + r;
                int ct = wn*32 + ni*16 + col;
                OS[rt*LDO + ct] = acc[mi][ni][r];
            }
        }
    }
    __syncthreads();
    {
        int rt = t >> 2, c0 = (t & 3)*16;          // 16 floats = 64 B per thread
        int row = m0 + rt, c = n0 + c0;
        const float* lp = &OS[rt*LDO + c0];
        const float* sp = skip + (size_t)row*DM + c;
        float* gp = C + (size_t)row*DM + c;
        #pragma unroll
        for (int j = 0; j < 4; ++j) {
            float4 a = *(const float4*)(lp + j*4);
            float4 s = *(const float4*)(sp + j*4);
            a.x += s.x; a.y += s.y; a.z += s.z; a.w += s.w;
            *(float4*)(gp + j*4) = a;
        }
    }
}

extern "C" void kernel_launch(void* const* d_in, const int* in_sizes, int n_in,
                              void* d_out, int out_size, void* d_ws, size_t ws_size,
                              hipStream_t stream) {
    const float* x      = (const float*)d_in[0];
    const float* pos    = (const float*)d_in[1];
    const float* cond   = (const float*)d_in[2];
    const float* w_norm = (const float*)d_in[3];
    const float* w_qkv  = (const float*)d_in[4];
    const float* w_out  = (const float*)d_in[5];
    float* out = (float*)d_out;
    char* base = (char*)d_ws;

    const size_t SZH = (size_t)NPIX*DM*2;   // fp16 [pix][256]: 2,359,296 B
    const size_t PAD = 4096;                // attn edge reads overrun <=2 pixels
    float*    scale  = (float*)(base);
    _Float16* qh     = (_Float16*)(base + PAD);
    _Float16* kh     = (_Float16*)(base + PAD + 1*(SZH+PAD));
    _Float16* vh     = (_Float16*)(base + PAD + 2*(SZH+PAD));
    _Float16* obuf_h = (_Float16*)(base + PAD + 3*(SZH+PAD));
    _Float16* wqkv_h = (_Float16*)(base + PAD + 4*(SZH+PAD));
    _Float16* wout_h = (_Float16*)(base + PAD + 4*(SZH+PAD) + 786432);

    prep_kernel<<<dim3(48), 256, 0, stream>>>(cond, w_norm, w_qkv, w_out,
                                              scale, wqkv_h, wout_h);
    gemm_qkv_fused<<<dim3(NPIX/64, 6), 256, 0, stream>>>(x, scale, wqkv_h, pos, qh, kh, vh);
    attn_mfma<<<dim3(36, N_B*NH), 256, 0, stream>>>(qh, kh, vh, obuf_h);
    gemm_out_f16<<<dim3(NPIX/64, DM/64), 256, 0, stream>>>(obuf_h, wout_h, out, x);
}

// Round 5
// 101.990 us; speedup vs baseline: 1.0229x; 1.0229x over previous
//
#include <hip/hip_runtime.h>
#include <math.h>

#define N_B 2
#define HH 48
#define WW 48
#define DM 256
#define NH 4
#define EH 64
#define KS 7
#define NPIX (N_B*HH*WW)    // 4608

typedef _Float16 half8 __attribute__((ext_vector_type(8)));
typedef _Float16 half4v __attribute__((ext_vector_type(4)));
typedef float float4v __attribute__((ext_vector_type(4)));

// ---------------- prep: scale = cond @ w_norm.T + 1, and fp32->fp16 weights ----------------
__global__ __launch_bounds__(256) void prep_kernel(const float* __restrict__ cond,
                                                   const float* __restrict__ w_norm,
                                                   const float* __restrict__ w_qkv,
                                                   const float* __restrict__ w_out,
                                                   float* __restrict__ scale,
                                                   _Float16* __restrict__ wqkv_h,
                                                   _Float16* __restrict__ wout_h) {
    int bid = blockIdx.x, t = threadIdx.x;
    if (bid < 16) {
        int wave = t >> 6, lane = t & 63;
        int b = bid >> 3;
        int d = (bid & 7)*32 + wave*8 + (lane >> 3);
        int l8 = lane & 7;
        const float4* wr4 = (const float4*)(w_norm + (size_t)d*DM) + l8*8;
        const float4* c4  = (const float4*)(cond + (size_t)b*DM) + l8*8;
        float acc = 0.f;
        #pragma unroll
        for (int j = 0; j < 8; ++j) {
            float4 w = wr4[j], c = c4[j];
            acc += w.x*c.x + w.y*c.y + w.z*c.z + w.w*c.w;
        }
        acc += __shfl_xor(acc, 1, 64);
        acc += __shfl_xor(acc, 2, 64);
        acc += __shfl_xor(acc, 4, 64);
        if (l8 == 0) scale[b*DM + d] = acc + 1.0f;
    } else if (bid < 40) {
        int job = bid - 16;
        const float* src = w_qkv + (size_t)job*8192;
        _Float16* dst = wqkv_h + (size_t)job*8192;
        #pragma unroll
        for (int j = 0; j < 8; ++j) {
            int idx = (j*256 + t)*4;
            float4 v = *(const float4*)(src + idx);
            half4v h;
            h[0] = (_Float16)v.x; h[1] = (_Float16)v.y;
            h[2] = (_Float16)v.z; h[3] = (_Float16)v.w;
            *(half4v*)(dst + idx) = h;
        }
    } else {
        int job = bid - 40;
        const float* src = w_out + (size_t)job*8192;
        _Float16* dst = wout_h + (size_t)job*8192;
        #pragma unroll
        for (int j = 0; j < 8; ++j) {
            int idx = (j*256 + t)*4;
            float4 v = *(const float4*)(src + idx);
            half4v h;
            h[0] = (_Float16)v.x; h[1] = (_Float16)v.y;
            h[2] = (_Float16)v.z; h[3] = (_Float16)v.w;
            *(half4v*)(dst + idx) = h;
        }
    }
}

// ---------------- fused RMSNorm + QKV GEMM + RoPE (fp16 B) ----------------
// 64x128 tile, full-K A in LDS (RMS computed in-block), double-buffered B,
// 1 barrier per K-step, waves 2x2 over (M,N): 8 MFMA per barrier per wave.
__global__ __launch_bounds__(256) void gemm_qkv_fused(const float* __restrict__ x,
                                                      const float* __restrict__ scale,
                                                      const _Float16* __restrict__ B,
                                                      const float* __restrict__ pos,
                                                      _Float16* __restrict__ qh,
                                                      _Float16* __restrict__ kh,
                                                      _Float16* __restrict__ vh) {
    const int LDA = 264, LDB = 40;
    __shared__ _Float16 As[64*LDA];
    __shared__ _Float16 Bs[2][128*LDB];
    int t = threadIdx.x;
    int wave = t >> 6, lane = t & 63;
    int m0 = blockIdx.x*64;
    int n0 = blockIdx.y*128;            // by in 0..5
    int b  = m0 / (HH*WW);

    // ---- load x rows, RMS-normalize, write fp16 As (full K) ----
    {
        int tr = t >> 2, c4i = t & 3;   // 4 threads per row
        const float4* xr = (const float4*)(x + (size_t)(m0 + tr)*DM);
        float4 xv[16];
        float ss = 0.f;
        #pragma unroll
        for (int j = 0; j < 16; ++j) {
            xv[j] = xr[c4i + j*4];
            ss += xv[j].x*xv[j].x + xv[j].y*xv[j].y + xv[j].z*xv[j].z + xv[j].w*xv[j].w;
        }
        ss += __shfl_xor(ss, 1, 64);
        ss += __shfl_xor(ss, 2, 64);
        float r = rsqrtf(ss*(1.0f/DM) + 1e-6f);
        const float* sc = scale + b*DM;
        #pragma unroll
        for (int j = 0; j < 16; ++j) {
            int c = (c4i + j*4)*4;
            float4 s4 = *(const float4*)(sc + c);
            half4v h;
            h[0] = (_Float16)(xv[j].x * s4.x * r);
            h[1] = (_Float16)(xv[j].y * s4.y * r);
            h[2] = (_Float16)(xv[j].z * s4.z * r);
            h[3] = (_Float16)(xv[j].w * s4.w * r);
            *(half4v*)&As[tr*LDA + c] = h;
        }
    }
    // ---- stage Bs[0]: 128 rows x 32 k (half8 copies) ----
    int br = t >> 1, kk = (t & 1)*16;
    {
        const _Float16* bp = B + (size_t)(n0 + br)*DM + kk;
        *(half8*)&Bs[0][br*LDB + kk]     = *(const half8*)bp;
        *(half8*)&Bs[0][br*LDB + kk + 8] = *(const half8*)(bp + 8);
    }
    __syncthreads();

    float4v acc[2][4];
    #pragma unroll
    for (int mi = 0; mi < 2; ++mi)
        #pragma unroll
        for (int ni = 0; ni < 4; ++ni) acc[mi][ni] = (float4v){0.f,0.f,0.f,0.f};

    int frow = lane & 15, kq = (lane >> 4)*8;
    int wm = wave >> 1, wn = wave & 1;

    for (int it = 0; it < 8; ++it) {
        int cur = it & 1;
        half8 nb0, nb1;
        if (it < 7) {
            const _Float16* bp = B + (size_t)(n0 + br)*DM + (it + 1)*32 + kk;
            nb0 = *(const half8*)bp;
            nb1 = *(const half8*)(bp + 8);
        }
        int ka = it*32 + kq;
        half8 af0 = *(const half8*)&As[(wm*32 +  0 + frow)*LDA + ka];
        half8 af1 = *(const half8*)&As[(wm*32 + 16 + frow)*LDA + ka];
        #pragma unroll
        for (int ni = 0; ni < 4; ++ni) {
            half8 bf = *(const half8*)&Bs[cur][(wn*64 + ni*16 + frow)*LDB + kq];
            acc[0][ni] = __builtin_amdgcn_mfma_f32_16x16x32_f16(af0, bf, acc[0][ni], 0, 0, 0);
            acc[1][ni] = __builtin_amdgcn_mfma_f32_16x16x32_f16(af1, bf, acc[1][ni], 0, 0, 0);
        }
        if (it < 7) {
            *(half8*)&Bs[cur^1][br*LDB + kk]     = nb0;
            *(half8*)&Bs[cur^1][br*LDB + kk + 8] = nb1;
            __syncthreads();
        }
    }

    // Epilogue: sel from by>>1; head = (by&1)*2 + wn; e = ni*16 + col.
    int sel  = blockIdx.y >> 1;
    int head = (blockIdx.y & 1)*2 + wn;
    _Float16* outp = (sel == 0) ? qh : (sel == 1) ? kh : vh;
    int col = lane & 15, rbase = (lane >> 4)*4;
    float freq = __expf(1.14472988585f + (float)(col & 7) * 0.287823136624f); // pi * 10^(mf/8)
    #pragma unroll
    for (int mi = 0; mi < 2; ++mi) {
        #pragma unroll
        for (int r = 0; r < 4; ++r) {
            int pix = m0 + wm*32 + mi*16 + rbase + r;
            float v0 = acc[mi][0][r], v1 = acc[mi][1][r], v2 = acc[mi][2][r], v3 = acc[mi][3][r];
            if (sel < 2) {
                int hw = pix % (HH*WW);
                float p = (col < 8) ? pos[hw*2] : pos[hw*2+1];
                float sn, cs;
                __sincosf(p*freq, &sn, &cs);
                float o0 = v0*cs - v1*sn;
                float o1 = v1*cs + v0*sn;
                v0 = o0; v1 = o1;
                if (sel == 0) { v0*=0.125f; v1*=0.125f; v2*=0.125f; v3*=0.125f; }
            }
            size_t base = (size_t)pix*DM + head*EH;
            outp[base +  0 + col] = (_Float16)v0;
            outp[base + 16 + col] = (_Float16)v1;
            outp[base + 32 + col] = (_Float16)v2;
            outp[base + 48 + col] = (_Float16)v3;
        }
    }
}

// ---------------- MFMA neighborhood attention (deferred 1/sum) ----------------
__global__ __launch_bounds__(256) void attn_mfma(const _Float16* __restrict__ qg,
                                                 const _Float16* __restrict__ kg,
                                                 const _Float16* __restrict__ vg,
                                                 _Float16* __restrict__ obuf) {
    __shared__ _Float16 VT[64*232];   // [d][nb]
    __shared__ _Float16 SP[64*232];   // [q][nb]
    int t = threadIdx.x;
    int wave = t >> 6, lane = t & 63;
    int col = lane & 15, quad = lane >> 4;
    int ty = blockIdx.x / 6, tx = blockIdx.x % 6;
    int b = blockIdx.y >> 2, head = blockIdx.y & 3;
    int qh0 = ty*8, qw0 = tx*8;
    int rh0 = min(max(qh0-3, 0), HH-14);
    int rw0 = min(max(qw0-3, 0), WW-14);

    {
        int nbl = t & 31;
        int e0  = (t >> 5) * 8;
        #pragma unroll
        for (int pass = 0; pass < 7; ++pass) {
            int nb = pass*32 + nbl;
            int nr = nb >> 4, nc = nb & 15;
            int pix = (b*HH + rh0+nr)*WW + rw0 + nc;
            half8 vv = *(const half8*)(vg + (size_t)pix*DM + head*EH + e0);
            #pragma unroll
            for (int i = 0; i < 8; ++i)
                VT[(e0+i)*232 + nb] = vv[i];
        }
    }

    int qidx_a = wave*16 + col;
    int pixq = (b*HH + qh0 + (qidx_a>>3))*WW + qw0 + (qidx_a & 7);
    const _Float16* qp = qg + (size_t)pixq*DM + head*EH;
    half8 qf0 = *(const half8*)(qp + quad*8);
    half8 qf1 = *(const half8*)(qp + 32 + quad*8);

    float4v s[14];
    #pragma unroll
    for (int nr = 0; nr < 14; ++nr) {
        int pixk = (b*HH + rh0+nr)*WW + rw0 + col;
        const _Float16* kp = kg + (size_t)pixk*DM + head*EH;
        half8 kf0 = *(const half8*)(kp + quad*8);
        half8 kf1 = *(const half8*)(kp + 32 + quad*8);
        float4v a = (float4v){0.f,0.f,0.f,0.f};
        a = __builtin_amdgcn_mfma_f32_16x16x32_f16(qf0, kf0, a, 0, 0, 0);
        a = __builtin_amdgcn_mfma_f32_16x16x32_f16(qf1, kf1, a, 0, 0, 0);
        s[nr] = a;
    }

    int sh_[4], uw_[4];
    #pragma unroll
    for (int r = 0; r < 4; ++r) {
        int qidx = wave*16 + quad*4 + r;
        int qhh = qh0 + (qidx>>3), qww = qw0 + (qidx & 7);
        sh_[r] = min(max(qhh-3, 0), HH-KS);
        int sw_ = min(max(qww-3, 0), WW-KS);
        uw_[r] = rw0 + col - sw_;
    }
    #pragma unroll
    for (int nr = 0; nr < 14; ++nr)
        #pragma unroll
        for (int r = 0; r < 4; ++r) {
            int uh = rh0 + nr - sh_[r];
            bool ok = ((unsigned)uh < 7u) && ((unsigned)uw_[r] < 7u);
            s[nr][r] = ok ? s[nr][r] : -1e30f;
        }
    float rs4[4];
    #pragma unroll
    for (int r = 0; r < 4; ++r) {
        float m = s[0][r];
        #pragma unroll
        for (int nr = 1; nr < 14; ++nr) m = fmaxf(m, s[nr][r]);
        m = fmaxf(m, __shfl_xor(m, 1, 64));
        m = fmaxf(m, __shfl_xor(m, 2, 64));
        m = fmaxf(m, __shfl_xor(m, 4, 64));
        m = fmaxf(m, __shfl_xor(m, 8, 64));
        float sum = 0.f;
        #pragma unroll
        for (int nr = 0; nr < 14; ++nr) { float p = __expf(s[nr][r] - m); s[nr][r] = p; sum += p; }
        sum += __shfl_xor(sum, 1, 64);
        sum += __shfl_xor(sum, 2, 64);
        sum += __shfl_xor(sum, 4, 64);
        sum += __shfl_xor(sum, 8, 64);
        rs4[r] = 1.f / sum;
        #pragma unroll
        for (int nr = 0; nr < 14; ++nr)
            SP[(wave*16 + quad*4 + r)*232 + nr*16 + col] = (_Float16)s[nr][r];
    }
    __syncthreads();

    float4v o[4];
    #pragma unroll
    for (int dt = 0; dt < 4; ++dt) o[dt] = (float4v){0.f,0.f,0.f,0.f};
    #pragma unroll
    for (int ks = 0; ks < 7; ++ks) {
        half8 pa = *(const half8*)&SP[(wave*16 + col)*232 + ks*32 + quad*8];
        #pragma unroll
        for (int dt = 0; dt < 4; ++dt) {
            half8 vf = *(const half8*)&VT[(dt*16 + col)*232 + ks*32 + quad*8];
            o[dt] = __builtin_amdgcn_mfma_f32_16x16x32_f16(pa, vf, o[dt], 0, 0, 0);
        }
    }
    #pragma unroll
    for (int r = 0; r < 4; ++r) {
        int qidx = wave*16 + quad*4 + r;
        int pix = (b*HH + qh0 + (qidx>>3))*WW + qw0 + (qidx & 7);
        #pragma unroll
        for (int dt = 0; dt < 4; ++dt)
            obuf[(size_t)pix*DM + head*EH + dt*16 + col] = (_Float16)(o[dt][r] * rs4[r]);
    }
}

// ---------------- out GEMM: C = obuf @ w_out^T + skip (fp16 B) ----------------
__global__ __launch_bounds__(256) void gemm_out_f16(const _Float16* __restrict__ A,
                                                    const _Float16* __restrict__ B,
                                                    float* __restrict__ C,
                                                    const float* __restrict__ skip) {
    const int LDA = 264, LDB = 40;
    __shared__ _Float16 As[64*LDA];
    __shared__ _Float16 Bs[2][64*LDB];
    int t = threadIdx.x;
    int wave = t >> 6, lane = t & 63;
    int m0 = blockIdx.x*64, n0 = blockIdx.y*64;

    // stage full A tile (fp16 copy)
    {
        int tr = t >> 2, c8 = (t & 3)*8;
        const _Float16* ap = A + (size_t)(m0 + tr)*DM;
        #pragma unroll
        for (int j = 0; j < 8; ++j)
            *(half8*)&As[tr*LDA + c8 + j*32] = *(const half8*)(ap + c8 + j*32);
    }
    // stage Bs[0]: 64 rows x 32 k (half8 copy)
    int br = t >> 2, kk = (t & 3)*8;
    *(half8*)&Bs[0][br*LDB + kk] = *(const half8*)(B + (size_t)(n0 + br)*DM + kk);
    __syncthreads();

    float4v acc[2][2];
    #pragma unroll
    for (int mi = 0; mi < 2; ++mi)
        #pragma unroll
        for (int ni = 0; ni < 2; ++ni) acc[mi][ni] = (float4v){0.f,0.f,0.f,0.f};

    int frow = lane & 15, kq = (lane >> 4)*8;
    int wm = wave >> 1, wn = wave & 1;

    for (int it = 0; it < 8; ++it) {
        int cur = it & 1;
        half8 nb;
        if (it < 7)
            nb = *(const half8*)(B + (size_t)(n0 + br)*DM + (it + 1)*32 + kk);
        int ka = it*32 + kq;
        half8 af0 = *(const half8*)&As[(wm*32 +  0 + frow)*LDA + ka];
        half8 af1 = *(const half8*)&As[(wm*32 + 16 + frow)*LDA + ka];
        #pragma unroll
        for (int ni = 0; ni < 2; ++ni) {
            half8 bf = *(const half8*)&Bs[cur][(wn*32 + ni*16 + frow)*LDB + kq];
            acc[0][ni] = __builtin_amdgcn_mfma_f32_16x16x32_f16(af0, bf, acc[0][ni], 0, 0, 0);
            acc[1][ni] = __builtin_amdgcn_mfma_f32_16x16x32_f16(af1, bf, acc[1][ni], 0, 0, 0);
        }
        if (it < 7) {
            *(half8*)&Bs[cur^1][br*LDB + kk] = nb;
            __syncthreads();
        }
    }

    int col = lane & 15, rbase = (lane >> 4)*4;
    #pragma unroll
    for (int mi = 0; mi < 2; ++mi) {
        #pragma unroll
        for (int ni = 0; ni < 2; ++ni) {
            #pragma unroll
            for (int r = 0; r < 4; ++r) {
                int row = m0 + wm*32 + mi*16 + rbase + r;
                int c   = n0 + wn*32 + ni*16 + col;
                C[(size_t)row*DM + c] = acc[mi][ni][r] + skip[(size_t)row*DM + c];
            }
        }
    }
}

extern "C" void kernel_launch(void* const* d_in, const int* in_sizes, int n_in,
                              void* d_out, int out_size, void* d_ws, size_t ws_size,
                              hipStream_t stream) {
    const float* x      = (const float*)d_in[0];
    const float* pos    = (const float*)d_in[1];
    const float* cond   = (const float*)d_in[2];
    const float* w_norm = (const float*)d_in[3];
    const float* w_qkv  = (const float*)d_in[4];
    const float* w_out  = (const float*)d_in[5];
    float* out = (float*)d_out;
    char* base = (char*)d_ws;

    const size_t SZH = (size_t)NPIX*DM*2;   // fp16 [pix][256]: 2,359,296 B
    const size_t PAD = 4096;                // attn edge reads overrun <=2 pixels
    float*    scale  = (float*)(base);
    _Float16* qh     = (_Float16*)(base + PAD);
    _Float16* kh     = (_Float16*)(base + PAD + 1*(SZH+PAD));
    _Float16* vh     = (_Float16*)(base + PAD + 2*(SZH+PAD));
    _Float16* obuf_h = (_Float16*)(base + PAD + 3*(SZH+PAD));
    _Float16* wqkv_h = (_Float16*)(base + PAD + 4*(SZH+PAD));
    _Float16* wout_h = (_Float16*)(base + PAD + 4*(SZH+PAD) + 786432);

    prep_kernel<<<dim3(48), 256, 0, stream>>>(cond, w_norm, w_qkv, w_out,
                                              scale, wqkv_h, wout_h);
    gemm_qkv_fused<<<dim3(NPIX/64, 6), 256, 0, stream>>>(x, scale, wqkv_h, pos, qh, kh, vh);
    attn_mfma<<<dim3(36, N_B*NH), 256, 0, stream>>>(qh, kh, vh, obuf_h);
    gemm_out_f16<<<dim3(NPIX/64, DM/64), 256, 0, stream>>>(obuf_h, wout_h, out, x);
}